// Round 10
// baseline (190.444 us; speedup 1.0000x reference)
//
#include <hip/hip_runtime.h>
#include <hip/hip_cooperative_groups.h>
#include <math.h>

namespace cg = cooperative_groups;

// force = MLP(|dr|) is piecewise-linear in the scalar edge length -> dense
// fp32 table of force(d) parameterized by u = d/(1+d) (data-independent
// grid, no max-reduction pass).
//
// Round-10: round-9 cooperative-fusion design, compile fix only (explicit
// (void*) casts in the kernel-args array; const T** -> void* is illegal).
//  A: 391 blocks bin 2048-edge chunks by dst-range (counting sort into
//     per-chunk regions, entry float4{dloc,dx,dy,u}, no global atomics);
//     256 other blocks build the 4096-entry force table (16 pts each).
//  B: 392 (range r x slice p) tiles: dense consume via LDS run-prefix +
//     binary search, table lerp, 16 KB LDS accumulate, store partial p.
//  C: out = -gamma*v + sum of 8 partials.
// Fallback (ws too small / coop launch fails): table + direct-atomic path.

#define M_TAB 4096
#define INV_MTAB (1.0f / 4096.0f)
#define EPSF 1e-12f
#define N_OUT 200000
#define RANGE_N 2048
#define RSHIFT 11
#define NBUCK 64
#define P_SL 8
#define BCHUNK 2048
#define TPTS 16
#define G_BLK 512
#define NTHR 512
#define MAXRUN 52

// Table builder: thread j(<128) = neuron j, TPTS grid points per task.
// All threads of the block must enter (uniform barriers).
__device__ __forceinline__ void build_table16(
    int base, int tid, const float* __restrict__ W0,
    const float* __restrict__ b0, const float* __restrict__ W1,
    const float* __restrict__ b1, const float* __restrict__ W2,
    const float* __restrict__ b2, const float* __restrict__ W3,
    const float* __restrict__ b3, float* __restrict__ table,
    float* bufA, float* bufB) {
  const int j = tid;
  if (j < 128) {
    float w = W0[j], b = b0[j];
#pragma unroll
    for (int p = 0; p < TPTS; ++p) {
      float u = (float)(base + p) * INV_MTAB;
      float dd = u / (1.f - u);
      bufA[j * TPTS + p] = fmaxf(fmaf(dd, w, b), 0.f);
    }
  }
  __syncthreads();
  float acc[TPTS];
  if (j < 128) {
    float b = b1[j];
#pragma unroll
    for (int p = 0; p < TPTS; ++p) acc[p] = b;
#pragma unroll 4
    for (int k = 0; k < 128; ++k) {
      float w = W1[k * 128 + j];
#pragma unroll
      for (int q = 0; q < 4; ++q) {
        float4 h = *(const float4*)&bufA[k * TPTS + q * 4];
        acc[q * 4 + 0] = fmaf(h.x, w, acc[q * 4 + 0]);
        acc[q * 4 + 1] = fmaf(h.y, w, acc[q * 4 + 1]);
        acc[q * 4 + 2] = fmaf(h.z, w, acc[q * 4 + 2]);
        acc[q * 4 + 3] = fmaf(h.w, w, acc[q * 4 + 3]);
      }
    }
  }
  __syncthreads();
  if (j < 128) {
#pragma unroll
    for (int p = 0; p < TPTS; ++p) bufB[j * TPTS + p] = fmaxf(acc[p], 0.f);
  }
  __syncthreads();
  if (j < 128) {
    float b = b2[j];
#pragma unroll
    for (int p = 0; p < TPTS; ++p) acc[p] = b;
#pragma unroll 4
    for (int k = 0; k < 128; ++k) {
      float w = W2[k * 128 + j];
#pragma unroll
      for (int q = 0; q < 4; ++q) {
        float4 h = *(const float4*)&bufB[k * TPTS + q * 4];
        acc[q * 4 + 0] = fmaf(h.x, w, acc[q * 4 + 0]);
        acc[q * 4 + 1] = fmaf(h.y, w, acc[q * 4 + 1]);
        acc[q * 4 + 2] = fmaf(h.z, w, acc[q * 4 + 2]);
        acc[q * 4 + 3] = fmaf(h.w, w, acc[q * 4 + 3]);
      }
    }
  }
  __syncthreads();
  if (j < 128) {
    float w3 = W3[j];
#pragma unroll
    for (int p = 0; p < TPTS; ++p)
      bufA[j * TPTS + p] = fmaxf(acc[p], 0.f) * w3;
  }
  __syncthreads();
  for (int s = 64; s > 0; s >>= 1) {
    if (j < s) {
#pragma unroll
      for (int p = 0; p < TPTS; ++p)
        bufA[j * TPTS + p] += bufA[(j + s) * TPTS + p];
    }
    __syncthreads();
  }
  if (j < TPTS) table[base + j] = bufA[j] + b3[0];
}

__global__ __launch_bounds__(NTHR, 4) void kfused(
    const float* __restrict__ x, const int* __restrict__ src,
    const int* __restrict__ dst, const float* __restrict__ v,
    const float* __restrict__ gamma, const float* __restrict__ W0,
    const float* __restrict__ b0, const float* __restrict__ W1,
    const float* __restrict__ b1, const float* __restrict__ W2,
    const float* __restrict__ b2, const float* __restrict__ W3,
    const float* __restrict__ b3, float4* __restrict__ binData,
    int* __restrict__ cntTab, int* __restrict__ offTab,
    float* __restrict__ table, float* __restrict__ partial,
    float* __restrict__ out, int E, int n_nodes, int NB) {
  __shared__ float smem[4096];  // 16 KB: bufA/bufB (table) or acc (scatter)
  __shared__ int cntL[NBUCK];
  __shared__ int offL[NBUCK];
  __shared__ int runStart[MAXRUN];
  __shared__ int pref[MAXRUN + 1];
  const int tid = threadIdx.x;
  cg::grid_group grid = cg::this_grid();

  // ---------------- Phase A: bin + table ----------------
  const int ntask = NB + M_TAB / TPTS;
  for (int task = blockIdx.x; task < ntask; task += gridDim.x) {
    __syncthreads();  // protect smem/cntL reuse across task iterations
    if (task < NB) {
      if (tid < NBUCK) cntL[tid] = 0;
      __syncthreads();
      const int e0 = task * BCHUNK + tid * 4;
      int msrc[4], mdst[4], mrank[4];
      float mdx[4], mdy[4], mu[4];
      if (e0 + 3 < E) {
        int4 a = *(const int4*)(src + e0);
        int4 c = *(const int4*)(dst + e0);
        msrc[0] = a.x; msrc[1] = a.y; msrc[2] = a.z; msrc[3] = a.w;
        mdst[0] = c.x; mdst[1] = c.y; mdst[2] = c.z; mdst[3] = c.w;
      } else {
#pragma unroll
        for (int i = 0; i < 4; ++i) {
          bool vv = (e0 + i < E);
          msrc[i] = vv ? src[e0 + i] : 0;
          mdst[i] = vv ? dst[e0 + i] : -1;
        }
      }
#pragma unroll
      for (int i = 0; i < 4; ++i) {
        if (mdst[i] >= 0) {
          float2 xs = ((const float2*)x)[msrc[i]];
          float2 xt = ((const float2*)x)[mdst[i]];
          mdx[i] = xt.x - xs.x;
          mdy[i] = xt.y - xs.y;
          float d = sqrtf(fmaf(mdx[i], mdx[i], mdy[i] * mdy[i]));
          mu[i] = d / (1.f + d);
          mrank[i] = atomicAdd(&cntL[mdst[i] >> RSHIFT], 1);
        }
      }
      __syncthreads();
      if (tid == 0) {
        int s = 0;
#pragma unroll
        for (int k = 0; k < NBUCK; ++k) {
          offL[k] = s;
          s += cntL[k];
        }
      }
      __syncthreads();
      if (tid < NBUCK) {
        cntTab[task * NBUCK + tid] = cntL[tid];
        offTab[task * NBUCK + tid] = offL[tid];
      }
      float4* gout = binData + (size_t)task * BCHUNK;
#pragma unroll
      for (int i = 0; i < 4; ++i) {
        if (mdst[i] >= 0) {
          gout[offL[mdst[i] >> RSHIFT] + mrank[i]] =
              make_float4(__int_as_float(mdst[i] & (RANGE_N - 1)), mdx[i],
                          mdy[i], mu[i]);
        }
      }
    } else {
      build_table16((task - NB) * TPTS, tid, W0, b0, W1, b1, W2, b2, W3, b3,
                    table, smem, smem + 2048);
    }
  }
  grid.sync();

  // ---------------- Phase B: scatter ----------------
  const int NR = (n_nodes + RANGE_N - 1) / RANGE_N;
  for (int tile = blockIdx.x; tile < NR * P_SL; tile += gridDim.x) {
    const int p = tile & (P_SL - 1);
    const int r = tile >> 3;
    float* acc = smem;
    for (int i = tid; i < RANGE_N * 2; i += NTHR) acc[i] = 0.f;
    const int nrun = (NB - p + P_SL - 1) / P_SL;
    for (int j = tid; j < nrun; j += NTHR) {
      int b = p + j * P_SL;
      runStart[j] = b * BCHUNK + offTab[b * NBUCK + r];
      pref[j + 1] = cntTab[b * NBUCK + r];
    }
    __syncthreads();
    if (tid == 0) {
      pref[0] = 0;
      for (int j = 0; j < nrun; ++j) pref[j + 1] += pref[j];
    }
    __syncthreads();
    const int T = pref[nrun];
    for (int g = tid; g < T; g += NTHR) {
      int lo = 0, hi = nrun;
      while (hi - lo > 1) {
        int mid = (lo + hi) >> 1;
        if (pref[mid] <= g) lo = mid; else hi = mid;
      }
      float4 ent = binData[(size_t)runStart[lo] + (g - pref[lo])];
      int dloc = __float_as_int(ent.x);
      float u = ent.w;
      float idxf = u * (float)M_TAB;
      int i0 = (int)idxf;
      if (i0 > M_TAB - 2) i0 = M_TAB - 2;
      float frac = idxf - (float)i0;
      float f0 = table[i0], f1 = table[i0 + 1];
      float f = fmaf(frac, f1 - f0, f0);
      float d = u / (1.f - u);
      float sc = f / fmaxf(d, EPSF);
      atomicAdd(&acc[dloc * 2], sc * ent.y);
      atomicAdd(&acc[dloc * 2 + 1], sc * ent.z);
    }
    __syncthreads();
    const int node0 = r * RANGE_N;
    const int cnt2 = min(RANGE_N, n_nodes - node0);
    float2* po = (float2*)(partial + (size_t)p * N_OUT) + node0;
    const float2* a2 = (const float2*)acc;
    for (int i = tid; i < cnt2; i += NTHR) po[i] = a2[i];
    __syncthreads();
  }
  grid.sync();

  // ---------------- Phase C: finish ----------------
  const float g = -gamma[0];
  const int n4 = N_OUT / 4;
  for (int i = blockIdx.x * NTHR + tid; i < n4; i += gridDim.x * NTHR) {
    float4 a = ((const float4*)v)[i];
    float4 o = make_float4(g * a.x, g * a.y, g * a.z, g * a.w);
#pragma unroll
    for (int c = 0; c < P_SL; ++c) {
      float4 pp = ((const float4*)partial)[(size_t)c * n4 + i];
      o.x += pp.x;
      o.y += pp.y;
      o.z += pp.z;
      o.w += pp.w;
    }
    ((float4*)out)[i] = o;
  }
}

// ---- Fallback path ----
__global__ __launch_bounds__(128) void k2_table(
    const float* __restrict__ W0, const float* __restrict__ b0,
    const float* __restrict__ W1, const float* __restrict__ b1,
    const float* __restrict__ W2, const float* __restrict__ b2,
    const float* __restrict__ W3, const float* __restrict__ b3,
    float* __restrict__ table) {
  __shared__ float bufA[2048];
  __shared__ float bufB[2048];
  build_table16(blockIdx.x * TPTS, threadIdx.x, W0, b0, W1, b1, W2, b2, W3,
                b3, table, bufA, bufB);
}

__global__ __launch_bounds__(256) void k0_init(const float* __restrict__ v,
                                               const float* __restrict__ gamma,
                                               float* __restrict__ out,
                                               int n) {
  int i = blockIdx.x * blockDim.x + threadIdx.x;
  if (i < n) out[i] = -gamma[0] * v[i];
}

__global__ __launch_bounds__(256) void k3_direct(
    const float* __restrict__ x, const int* __restrict__ src,
    const int* __restrict__ dst, const float* __restrict__ table,
    float* __restrict__ out, int E) {
  int e = blockIdx.x * blockDim.x + threadIdx.x;
  if (e >= E) return;
  int s = src[e], t = dst[e];
  float2 xs = ((const float2*)x)[s];
  float2 xt = ((const float2*)x)[t];
  float dx = xt.x - xs.x, dy = xt.y - xs.y;
  float d = sqrtf(fmaf(dx, dx, dy * dy));
  float u = d / (1.f + d);
  float idxf = u * (float)M_TAB;
  int i0 = (int)idxf;
  if (i0 > M_TAB - 2) i0 = M_TAB - 2;
  float frac = idxf - (float)i0;
  float f = fmaf(frac, table[i0 + 1] - table[i0], table[i0]);
  float sc = f / fmaxf(d, EPSF);
  atomicAdd(&out[2 * t + 0], sc * dx);
  atomicAdd(&out[2 * t + 1], sc * dy);
}

extern "C" void kernel_launch(void* const* d_in, const int* in_sizes, int n_in,
                              void* d_out, int out_size, void* d_ws,
                              size_t ws_size, hipStream_t stream) {
  const float* x = (const float*)d_in[0];
  const float* v = (const float*)d_in[1];
  const int* src = (const int*)d_in[2];
  const int* dst = (const int*)d_in[3];
  const float* gamma = (const float*)d_in[4];
  const float* W0 = (const float*)d_in[5];
  const float* b0 = (const float*)d_in[6];
  const float* W1 = (const float*)d_in[7];
  const float* b1 = (const float*)d_in[8];
  const float* W2 = (const float*)d_in[9];
  const float* b2 = (const float*)d_in[10];
  const float* W3 = (const float*)d_in[11];
  const float* b3 = (const float*)d_in[12];
  float* out = (float*)d_out;
  float* table = (float*)d_ws;

  int n_out = out_size;           // 200000
  int n_nodes = in_sizes[0] / 2;  // 100000
  int E = in_sizes[2];            // 800000

  const int NB = (E + BCHUNK - 1) / BCHUNK;  // 391
  size_t sz_tab = ((size_t)NB * NBUCK * 4 + 255) & ~(size_t)255;
  size_t off_cnt = 65536;
  size_t off_off = off_cnt + sz_tab;
  size_t off_part = off_off + sz_tab;
  size_t off_bin = off_part + (size_t)P_SL * N_OUT * 4;
  size_t need = off_bin + (size_t)NB * BCHUNK * 16;

  const int NR = (n_nodes + RANGE_N - 1) / RANGE_N;  // 49
  bool fast = (ws_size >= need) && (n_out == N_OUT) &&
              (n_out == 2 * n_nodes) && (NR <= NBUCK) &&
              (NB <= P_SL * MAXRUN);

  if (fast) {
    int* cntTab = (int*)((char*)d_ws + off_cnt);
    int* offTab = (int*)((char*)d_ws + off_off);
    float* partial = (float*)((char*)d_ws + off_part);
    float4* binData = (float4*)((char*)d_ws + off_bin);
    void* args[] = {(void*)&x,      (void*)&src,    (void*)&dst,
                    (void*)&v,      (void*)&gamma,  (void*)&W0,
                    (void*)&b0,     (void*)&W1,     (void*)&b1,
                    (void*)&W2,     (void*)&b2,     (void*)&W3,
                    (void*)&b3,     (void*)&binData, (void*)&cntTab,
                    (void*)&offTab, (void*)&table,  (void*)&partial,
                    (void*)&out,    (void*)&E,      (void*)&n_nodes,
                    (void*)&NB};
    hipError_t err = hipLaunchCooperativeKernel(
        (const void*)kfused, dim3(G_BLK), dim3(NTHR), args, 0, stream);
    if (err == hipSuccess) return;
    (void)hipGetLastError();  // clear, fall through to fallback
  }
  hipLaunchKernelGGL(k2_table, dim3(M_TAB / TPTS), dim3(128), 0, stream, W0,
                     b0, W1, b1, W2, b2, W3, b3, table);
  hipLaunchKernelGGL(k0_init, dim3((n_out + 255) / 256), dim3(256), 0, stream,
                     v, gamma, out, n_out);
  hipLaunchKernelGGL(k3_direct, dim3((E + 255) / 256), dim3(256), 0, stream,
                     x, src, dst, table, out, E);
}

// Round 11
// 66.823 us; speedup vs baseline: 2.8500x; 2.8500x over previous
//
#include <hip/hip_runtime.h>
#include <math.h>

// force = MLP(|dr|) is piecewise-linear in the scalar edge length -> dense
// fp32 table of force(d) parameterized by u = d/(1+d) (data-independent).
//
// Round-11: cooperative grid.sync measured ~85us/sync on gfx950 (r10:
// 190us, all pipes idle) -> back to plain dispatches, but only TWO:
//  kA (647 blocks x 512t): blocks <391 bin 2048-edge chunks by 512-node
//      bucket (counting sort into per-chunk regions, float4{dloc,dx,dy,u},
//      cnt/off stored TRANSPOSED [bucket][chunk] for coalesced consume);
//      blocks >=391 build the 4096-entry table (16 pts each).
//  kB (196 blocks x 512t): block r consumes ALL 391 runs of bucket r via
//      LDS run-prefix + binary search (dense lanes), accumulates in 4 KB
//      LDS, writes out = acc - gamma*v directly (NO partials, no 3rd pass).

#define M_TAB 4096
#define INV_MTAB (1.0f / 4096.0f)
#define EPSF 1e-12f
#define RANGE_N 512
#define RSHIFT 9
#define BCHUNK 2048
#define TPTS 16
#define NB_MAX 400
#define NBUCK_MAX 256

// Table builder: thread j(<128) = neuron j, TPTS grid points per task.
// All threads of the block must enter (uniform barriers).
__device__ __forceinline__ void build_table16(
    int base, int tid, const float* __restrict__ W0,
    const float* __restrict__ b0, const float* __restrict__ W1,
    const float* __restrict__ b1, const float* __restrict__ W2,
    const float* __restrict__ b2, const float* __restrict__ W3,
    const float* __restrict__ b3, float* __restrict__ table,
    float* bufA, float* bufB) {
  const int j = tid;
  if (j < 128) {
    float w = W0[j], b = b0[j];
#pragma unroll
    for (int p = 0; p < TPTS; ++p) {
      float u = (float)(base + p) * INV_MTAB;
      float dd = u / (1.f - u);
      bufA[j * TPTS + p] = fmaxf(fmaf(dd, w, b), 0.f);
    }
  }
  __syncthreads();
  float acc[TPTS];
  if (j < 128) {
    float b = b1[j];
#pragma unroll
    for (int p = 0; p < TPTS; ++p) acc[p] = b;
#pragma unroll 4
    for (int k = 0; k < 128; ++k) {
      float w = W1[k * 128 + j];
#pragma unroll
      for (int q = 0; q < 4; ++q) {
        float4 h = *(const float4*)&bufA[k * TPTS + q * 4];
        acc[q * 4 + 0] = fmaf(h.x, w, acc[q * 4 + 0]);
        acc[q * 4 + 1] = fmaf(h.y, w, acc[q * 4 + 1]);
        acc[q * 4 + 2] = fmaf(h.z, w, acc[q * 4 + 2]);
        acc[q * 4 + 3] = fmaf(h.w, w, acc[q * 4 + 3]);
      }
    }
  }
  __syncthreads();
  if (j < 128) {
#pragma unroll
    for (int p = 0; p < TPTS; ++p) bufB[j * TPTS + p] = fmaxf(acc[p], 0.f);
  }
  __syncthreads();
  if (j < 128) {
    float b = b2[j];
#pragma unroll
    for (int p = 0; p < TPTS; ++p) acc[p] = b;
#pragma unroll 4
    for (int k = 0; k < 128; ++k) {
      float w = W2[k * 128 + j];
#pragma unroll
      for (int q = 0; q < 4; ++q) {
        float4 h = *(const float4*)&bufB[k * TPTS + q * 4];
        acc[q * 4 + 0] = fmaf(h.x, w, acc[q * 4 + 0]);
        acc[q * 4 + 1] = fmaf(h.y, w, acc[q * 4 + 1]);
        acc[q * 4 + 2] = fmaf(h.z, w, acc[q * 4 + 2]);
        acc[q * 4 + 3] = fmaf(h.w, w, acc[q * 4 + 3]);
      }
    }
  }
  __syncthreads();
  if (j < 128) {
    float w3 = W3[j];
#pragma unroll
    for (int p = 0; p < TPTS; ++p)
      bufA[j * TPTS + p] = fmaxf(acc[p], 0.f) * w3;
  }
  __syncthreads();
  for (int s = 64; s > 0; s >>= 1) {
    if (j < s) {
#pragma unroll
      for (int p = 0; p < TPTS; ++p)
        bufA[j * TPTS + p] += bufA[(j + s) * TPTS + p];
    }
    __syncthreads();
  }
  if (j < TPTS) table[base + j] = bufA[j] + b3[0];
}

// kA: blocks < NB: bin chunk [b*2048, b*2048+2048); blocks >= NB: table.
__global__ __launch_bounds__(512) void kA(
    const float* __restrict__ x, const int* __restrict__ src,
    const int* __restrict__ dst, const float* __restrict__ W0,
    const float* __restrict__ b0, const float* __restrict__ W1,
    const float* __restrict__ b1, const float* __restrict__ W2,
    const float* __restrict__ b2, const float* __restrict__ W3,
    const float* __restrict__ b3, float4* __restrict__ binData,
    int* __restrict__ cntTab, int* __restrict__ offTab,
    float* __restrict__ table, int E, int NB, int NBUCK) {
  __shared__ float smem[4096];  // table bufA/bufB (16 KB)
  __shared__ int cntL[NBUCK_MAX];
  __shared__ int offL[NBUCK_MAX];
  const int tid = threadIdx.x;
  const int bid = blockIdx.x;

  if (bid < NB) {
    if (tid < NBUCK_MAX) cntL[tid] = 0;
    __syncthreads();
    const int e0 = bid * BCHUNK + tid * 4;
    int msrc[4], mdst[4], mrank[4];
    float mdx[4], mdy[4], mu[4];
    if (e0 + 3 < E) {
      int4 a = *(const int4*)(src + e0);
      int4 c = *(const int4*)(dst + e0);
      msrc[0] = a.x; msrc[1] = a.y; msrc[2] = a.z; msrc[3] = a.w;
      mdst[0] = c.x; mdst[1] = c.y; mdst[2] = c.z; mdst[3] = c.w;
    } else {
#pragma unroll
      for (int i = 0; i < 4; ++i) {
        bool vv = (e0 + i < E);
        msrc[i] = vv ? src[e0 + i] : 0;
        mdst[i] = vv ? dst[e0 + i] : -1;
      }
    }
#pragma unroll
    for (int i = 0; i < 4; ++i) {
      if (mdst[i] >= 0) {
        float2 xs = ((const float2*)x)[msrc[i]];
        float2 xt = ((const float2*)x)[mdst[i]];
        mdx[i] = xt.x - xs.x;
        mdy[i] = xt.y - xs.y;
        float d = sqrtf(fmaf(mdx[i], mdx[i], mdy[i] * mdy[i]));
        mu[i] = d / (1.f + d);
        mrank[i] = atomicAdd(&cntL[mdst[i] >> RSHIFT], 1);
      }
    }
    __syncthreads();
    if (tid == 0) {
      int s = 0;
      for (int k = 0; k < NBUCK; ++k) {
        offL[k] = s;
        s += cntL[k];
      }
    }
    __syncthreads();
    if (tid < NBUCK) {
      cntTab[tid * NB + bid] = cntL[tid];  // transposed: [bucket][chunk]
      offTab[tid * NB + bid] = offL[tid];
    }
    float4* gout = binData + (size_t)bid * BCHUNK;
#pragma unroll
    for (int i = 0; i < 4; ++i) {
      if (mdst[i] >= 0) {
        gout[offL[mdst[i] >> RSHIFT] + mrank[i]] =
            make_float4(__int_as_float(mdst[i] & (RANGE_N - 1)), mdx[i],
                        mdy[i], mu[i]);
      }
    }
  } else {
    build_table16((bid - NB) * TPTS, tid, W0, b0, W1, b1, W2, b2, W3, b3,
                  table, smem, smem + 2048);
  }
}

// kB: block r consumes all NB runs of bucket r; out = acc - gamma*v.
__global__ __launch_bounds__(512) void kB(
    const float4* __restrict__ binData, const int* __restrict__ cntTab,
    const int* __restrict__ offTab, const float* __restrict__ table,
    const float* __restrict__ v, const float* __restrict__ gamma,
    float* __restrict__ out, int NB, int n_nodes) {
  __shared__ float acc[RANGE_N * 2];  // 4 KB
  __shared__ int runStart[NB_MAX];
  __shared__ int pref[NB_MAX + 1];
  __shared__ int grp[64], gpre[64];
  const int tid = threadIdx.x;
  const int r = blockIdx.x;
  const int NSEG = (NB + 7) / 8;

  for (int i = tid; i < RANGE_N * 2; i += 512) acc[i] = 0.f;
  for (int j = tid; j < NB; j += 512) {
    runStart[j] = j * BCHUNK + offTab[r * NB + j];
    pref[j + 1] = cntTab[r * NB + j];
  }
  if (tid == 0) pref[0] = 0;
  __syncthreads();
  // two-level prefix over pref[1..NB]
  if (tid < NSEG) {
    int s = 0;
    int k0 = tid * 8, k1 = min(NB, k0 + 8);
    for (int k = k0; k < k1; ++k) {
      s += pref[k + 1];
      pref[k + 1] = s;
    }
    grp[tid] = s;
  }
  __syncthreads();
  if (tid == 0) {
    int s = 0;
    for (int t = 0; t < NSEG; ++t) {
      gpre[t] = s;
      s += grp[t];
    }
  }
  __syncthreads();
  if (tid < NSEG) {
    int g0 = gpre[tid];
    int k0 = tid * 8, k1 = min(NB, k0 + 8);
    for (int k = k0; k < k1; ++k) pref[k + 1] += g0;
  }
  __syncthreads();

  const int T = pref[NB];
  for (int g = tid; g < T; g += 512) {
    int lo = 0, hi = NB;
    while (hi - lo > 1) {
      int mid = (lo + hi) >> 1;
      if (pref[mid] <= g) lo = mid; else hi = mid;
    }
    float4 ent = binData[(size_t)runStart[lo] + (g - pref[lo])];
    int dloc = __float_as_int(ent.x);
    float u = ent.w;
    float idxf = u * (float)M_TAB;
    int i0 = (int)idxf;
    if (i0 > M_TAB - 2) i0 = M_TAB - 2;
    float frac = idxf - (float)i0;
    float f0 = table[i0], f1 = table[i0 + 1];
    float f = fmaf(frac, f1 - f0, f0);
    float d = u / (1.f - u);
    float sc = f / fmaxf(d, EPSF);
    atomicAdd(&acc[dloc * 2], sc * ent.y);
    atomicAdd(&acc[dloc * 2 + 1], sc * ent.z);
  }
  __syncthreads();

  const int node0 = r * RANGE_N;
  const int cnt2 = min(RANGE_N, n_nodes - node0);
  const float gm = -gamma[0];
  float2* po = (float2*)out + node0;
  const float2* pv = (const float2*)v + node0;
  const float2* a2 = (const float2*)acc;
  for (int i = tid; i < cnt2; i += 512) {
    float2 a = a2[i];
    float2 vv = pv[i];
    po[i] = make_float2(fmaf(gm, vv.x, a.x), fmaf(gm, vv.y, a.y));
  }
}

// ---- Fallback path (tiny d_ws only) ----
__global__ __launch_bounds__(128) void k2_table(
    const float* __restrict__ W0, const float* __restrict__ b0,
    const float* __restrict__ W1, const float* __restrict__ b1,
    const float* __restrict__ W2, const float* __restrict__ b2,
    const float* __restrict__ W3, const float* __restrict__ b3,
    float* __restrict__ table) {
  __shared__ float bufA[2048];
  __shared__ float bufB[2048];
  build_table16(blockIdx.x * TPTS, threadIdx.x, W0, b0, W1, b1, W2, b2, W3,
                b3, table, bufA, bufB);
}

__global__ __launch_bounds__(256) void k0_init(const float* __restrict__ v,
                                               const float* __restrict__ gamma,
                                               float* __restrict__ out,
                                               int n) {
  int i = blockIdx.x * blockDim.x + threadIdx.x;
  if (i < n) out[i] = -gamma[0] * v[i];
}

__global__ __launch_bounds__(256) void k3_direct(
    const float* __restrict__ x, const int* __restrict__ src,
    const int* __restrict__ dst, const float* __restrict__ table,
    float* __restrict__ out, int E) {
  int e = blockIdx.x * blockDim.x + threadIdx.x;
  if (e >= E) return;
  int s = src[e], t = dst[e];
  float2 xs = ((const float2*)x)[s];
  float2 xt = ((const float2*)x)[t];
  float dx = xt.x - xs.x, dy = xt.y - xs.y;
  float d = sqrtf(fmaf(dx, dx, dy * dy));
  float u = d / (1.f + d);
  float idxf = u * (float)M_TAB;
  int i0 = (int)idxf;
  if (i0 > M_TAB - 2) i0 = M_TAB - 2;
  float frac = idxf - (float)i0;
  float f = fmaf(frac, table[i0 + 1] - table[i0], table[i0]);
  float sc = f / fmaxf(d, EPSF);
  atomicAdd(&out[2 * t + 0], sc * dx);
  atomicAdd(&out[2 * t + 1], sc * dy);
}

extern "C" void kernel_launch(void* const* d_in, const int* in_sizes, int n_in,
                              void* d_out, int out_size, void* d_ws,
                              size_t ws_size, hipStream_t stream) {
  const float* x = (const float*)d_in[0];
  const float* v = (const float*)d_in[1];
  const int* src = (const int*)d_in[2];
  const int* dst = (const int*)d_in[3];
  const float* gamma = (const float*)d_in[4];
  const float* W0 = (const float*)d_in[5];
  const float* b0 = (const float*)d_in[6];
  const float* W1 = (const float*)d_in[7];
  const float* b1 = (const float*)d_in[8];
  const float* W2 = (const float*)d_in[9];
  const float* b2 = (const float*)d_in[10];
  const float* W3 = (const float*)d_in[11];
  const float* b3 = (const float*)d_in[12];
  float* out = (float*)d_out;
  float* table = (float*)d_ws;

  int n_out = out_size;           // 200000
  int n_nodes = in_sizes[0] / 2;  // 100000
  int E = in_sizes[2];            // 800000

  const int NB = (E + BCHUNK - 1) / BCHUNK;             // 391
  const int NBUCK = (n_nodes + RANGE_N - 1) / RANGE_N;  // 196
  size_t sz_tab = ((size_t)NB * NBUCK * 4 + 255) & ~(size_t)255;
  size_t off_cnt = 65536;
  size_t off_off = off_cnt + sz_tab;
  size_t off_bin = (off_off + sz_tab + 255) & ~(size_t)255;
  size_t need = off_bin + (size_t)NB * BCHUNK * 16;

  bool fast = (ws_size >= need) && (n_out == 2 * n_nodes) &&
              (NB <= NB_MAX) && (NBUCK <= NBUCK_MAX);

  if (fast) {
    int* cntTab = (int*)((char*)d_ws + off_cnt);
    int* offTab = (int*)((char*)d_ws + off_off);
    float4* binData = (float4*)((char*)d_ws + off_bin);
    hipLaunchKernelGGL(kA, dim3(NB + M_TAB / TPTS), dim3(512), 0, stream, x,
                       src, dst, W0, b0, W1, b1, W2, b2, W3, b3, binData,
                       cntTab, offTab, table, E, NB, NBUCK);
    hipLaunchKernelGGL(kB, dim3(NBUCK), dim3(512), 0, stream, binData, cntTab,
                       offTab, table, v, gamma, out, NB, n_nodes);
  } else {
    hipLaunchKernelGGL(k2_table, dim3(M_TAB / TPTS), dim3(128), 0, stream, W0,
                       b0, W1, b1, W2, b2, W3, b3, table);
    hipLaunchKernelGGL(k0_init, dim3((n_out + 255) / 256), dim3(256), 0,
                       stream, v, gamma, out, n_out);
    hipLaunchKernelGGL(k3_direct, dim3((E + 255) / 256), dim3(256), 0, stream,
                       x, src, dst, table, out, E);
  }
}